// Round 1
// baseline (4560.734 us; speedup 1.0000x reference)
//
#include <hip/hip_runtime.h>
#include <hip/hip_bf16.h>
#include <math.h>

// Problem constants
#define Bz 2
#define Tz 2048
#define Cz 1024
#define Hz 16
#define Dz 64      // HEAD_DIM
#define Rz 32      // ROPE_DIM
#define KVR 256
#define QR 512
#define DQK 96     // HEAD_DIM + ROPE_DIM
#define Mz (Bz*Tz)         // 4096 rows
#define BHT (Bz*Hz*Tz)     // 65536

// ---------------------------------------------------------------------------
// Generic fp32 tiled GEMM:  C = A(MxK) @ W(KxN)
// amode 0: A row-major.  amode 2: A is heads buffer (B,H,T,64) read as (m, k)
// omode 0: C row-major.  omode 1: scatter into (B,H,T,Dtot) at column offset
// ---------------------------------------------------------------------------
__device__ __forceinline__ float loadA(const float* __restrict__ A, int m, int kk,
                                       int K, int amode) {
    if (amode == 0) return A[(size_t)m * K + kk];
    // amode 2: heads layout (B,H,T,64) -> matrix (b*T+t, h*64+d)
    int b = m >> 11, t = m & (Tz - 1);
    int h = kk >> 6, d = kk & 63;
    return A[(((size_t)b * Hz + h) * Tz + t) * 64 + d];
}

__global__ __launch_bounds__(256) void gemm_f32(
    const float* __restrict__ A, const float* __restrict__ W, float* __restrict__ C,
    int M, int N, int K, int amode, int omode, int headDim, int Dtot, int off)
{
    __shared__ float As[16][65];
    __shared__ float Bs[16][65];
    int tid = threadIdx.x;
    int tx = tid & 15, ty = tid >> 4;
    int bm = blockIdx.x * 64;
    int bn = blockIdx.y * 64;

    float acc[4][4] = {};

    for (int k0 = 0; k0 < K; k0 += 16) {
        // A tile: 64 rows x 16 cols
        #pragma unroll
        for (int l = 0; l < 4; l++) {
            int idx = tid + l * 256;
            int r = idx >> 4, c = idx & 15;
            As[c][r] = loadA(A, bm + r, k0 + c, K, amode);
        }
        // B tile: 16 rows x 64 cols
        #pragma unroll
        for (int l = 0; l < 4; l++) {
            int idx = tid + l * 256;
            int n = idx & 63, c = idx >> 6;
            Bs[c][n] = W[(size_t)(k0 + c) * N + bn + n];
        }
        __syncthreads();
        #pragma unroll
        for (int kk = 0; kk < 16; kk++) {
            float a[4], b[4];
            #pragma unroll
            for (int i = 0; i < 4; i++) a[i] = As[kk][ty * 4 + i];
            #pragma unroll
            for (int j = 0; j < 4; j++) b[j] = Bs[kk][tx * 4 + j];
            #pragma unroll
            for (int i = 0; i < 4; i++)
                #pragma unroll
                for (int j = 0; j < 4; j++)
                    acc[i][j] = fmaf(a[i], b[j], acc[i][j]);
        }
        __syncthreads();
    }

    #pragma unroll
    for (int i = 0; i < 4; i++) {
        int m = bm + ty * 4 + i;
        #pragma unroll
        for (int j = 0; j < 4; j++) {
            int n = bn + tx * 4 + j;
            float v = acc[i][j];
            if (omode == 0) {
                C[(size_t)m * N + n] = v;
            } else {
                int b = m >> 11, t = m & (Tz - 1);
                int h = n / headDim, dd = n % headDim;
                C[((((size_t)b * Hz + h) * Tz + t) * Dtot) + off + dd] = v;
            }
        }
    }
}

// ---------------------------------------------------------------------------
// RMSNorm over rows of 256, in place, with gain g. One wave per row.
// ---------------------------------------------------------------------------
__global__ __launch_bounds__(256) void rmsnorm_k(float* __restrict__ kv,
                                                 const float* __restrict__ g)
{
    int row = blockIdx.x * 4 + (threadIdx.x >> 6);
    int lane = threadIdx.x & 63;
    float* p = kv + (size_t)row * 256;
    float v[4];
    float ss = 0.f;
    #pragma unroll
    for (int i = 0; i < 4; i++) { v[i] = p[lane + i * 64]; ss += v[i] * v[i]; }
    #pragma unroll
    for (int o = 32; o > 0; o >>= 1) ss += __shfl_xor(ss, o);
    float r = rsqrtf(ss * (1.f / 256.f) + 1e-6f);
    #pragma unroll
    for (int i = 0; i < 4; i++) p[lane + i * 64] = v[i] * r * g[lane + i * 64];
}

// ---------------------------------------------------------------------------
// RoPE in place on the [64..96) slice of q and k (both (B,H,T,96)).
// One thread per rotation pair. idx covers 2 * BHT * 16 threads.
// ---------------------------------------------------------------------------
__global__ __launch_bounds__(256) void rope_k(float* __restrict__ qb, float* __restrict__ kb)
{
    int idx = blockIdx.x * 256 + threadIdx.x;
    int j = idx & 15;
    int row = idx >> 4;          // 0 .. 2*BHT
    float* buf = (row >= BHT) ? kb : qb;
    if (row >= BHT) row -= BHT;
    int t = row & (Tz - 1);
    float inv = powf(10000.f, -(float)(2 * j) / 32.f);
    float ang = (float)t * inv;
    float c = cosf(ang), s = sinf(ang);
    float* pr = buf + (size_t)row * DQK + Dz;
    float x1 = pr[j], x2 = pr[j + 16];
    pr[j]      = x1 * c - x2 * s;
    pr[j + 16] = x2 * c + x1 * s;
}

// ---------------------------------------------------------------------------
// Causal flash attention. One 64-lane wave per (b,h,t) query row.
// q,k: (B,H,T,96); v,o: (B,H,T,64).
// ---------------------------------------------------------------------------
__global__ __launch_bounds__(64) void attn_k(const float* __restrict__ q,
                                             const float* __restrict__ k,
                                             const float* __restrict__ v,
                                             float* __restrict__ o)
{
    __shared__ float qs[DQK];
    __shared__ float ps[64];
    int bid = blockIdx.x;
    int t = bid & (Tz - 1);
    int bh = bid >> 11;
    int lane = threadIdx.x;
    const float scale = 0.10206207261596577f; // 1/sqrt(96)

    const float* qrow = q + ((size_t)bh * Tz + t) * DQK;
    for (int i = lane; i < DQK; i += 64) qs[i] = qrow[i] * scale;
    __syncthreads();

    const float* kb = k + (size_t)bh * Tz * DQK;
    const float* vb = v + (size_t)bh * Tz * 64;
    int nk = t + 1;

    float m = -INFINITY, l = 0.f, acc = 0.f;

    for (int kt0 = 0; kt0 < nk; kt0 += 64) {
        int key = kt0 + lane;
        float s = -INFINITY;
        if (key < nk) {
            const float* kr = kb + (size_t)key * DQK;
            float d0 = 0.f;
            #pragma unroll 8
            for (int d = 0; d < DQK; d++) d0 = fmaf(qs[d], kr[d], d0);
            s = d0;
        }
        float tm = s;
        #pragma unroll
        for (int o2 = 32; o2 > 0; o2 >>= 1) tm = fmaxf(tm, __shfl_xor(tm, o2));
        float mnew = fmaxf(m, tm);
        float sc = __expf(m - mnew);     // m=-inf first iter -> 0
        float p = (key < nk) ? __expf(s - mnew) : 0.f;
        float tp = p;
        #pragma unroll
        for (int o2 = 32; o2 > 0; o2 >>= 1) tp += __shfl_xor(tp, o2);
        l = l * sc + tp;
        m = mnew;
        ps[lane] = p;
        __syncthreads();
        acc *= sc;
        int lim = min(64, nk - kt0);
        for (int j = 0; j < lim; j++)
            acc = fmaf(ps[j], vb[(size_t)(kt0 + j) * 64 + lane], acc);
        __syncthreads();
    }
    o[((size_t)bh * Tz + t) * 64 + lane] = acc / l;
}

// ---------------------------------------------------------------------------
extern "C" void kernel_launch(void* const* d_in, const int* in_sizes, int n_in,
                              void* d_out, int out_size, void* d_ws, size_t ws_size,
                              hipStream_t stream)
{
    const float* x       = (const float*)d_in[0];
    const float* W_kv    = (const float*)d_in[1];
    const float* g_kv    = (const float*)d_in[2];
    const float* W_kdec  = (const float*)d_in[3];
    const float* W_vdec  = (const float*)d_in[4];
    const float* W_q     = (const float*)d_in[5];
    const float* W_qdec  = (const float*)d_in[6];
    const float* W_krope = (const float*)d_in[7];
    const float* W_qrope = (const float*)d_in[8];
    const float* W_o     = (const float*)d_in[9];
    float* out = (float*)d_out;

    float* ws   = (float*)d_ws;
    float* kv_n = ws;                           // 4096*256
    float* q_c  = kv_n + (size_t)Mz * KVR;      // 4096*512
    float* qb   = q_c  + (size_t)Mz * QR;       // BHT*96
    float* kb   = qb   + (size_t)BHT * DQK;     // BHT*96
    float* vb   = kb   + (size_t)BHT * DQK;     // BHT*64
    float* ob   = vb   + (size_t)BHT * 64;      // BHT*64

    dim3 blk(256);

    // kv_c = x @ W_kv
    gemm_f32<<<dim3(Mz/64, KVR/64), blk, 0, stream>>>(x, W_kv, kv_n, Mz, KVR, Cz, 0, 0, 0, 0, 0);
    // RMSNorm in place
    rmsnorm_k<<<dim3(Mz/4), blk, 0, stream>>>(kv_n, g_kv);
    // q_c = x @ W_q
    gemm_f32<<<dim3(Mz/64, QR/64), blk, 0, stream>>>(x, W_q, q_c, Mz, QR, Cz, 0, 0, 0, 0, 0);
    // k_content -> kb[...,0:64]
    gemm_f32<<<dim3(Mz/64, (Hz*Dz)/64), blk, 0, stream>>>(kv_n, W_kdec, kb, Mz, Hz*Dz, KVR, 0, 1, 64, DQK, 0);
    // v -> vb
    gemm_f32<<<dim3(Mz/64, (Hz*Dz)/64), blk, 0, stream>>>(kv_n, W_vdec, vb, Mz, Hz*Dz, KVR, 0, 1, 64, 64, 0);
    // q_content -> qb[...,0:64]
    gemm_f32<<<dim3(Mz/64, (Hz*Dz)/64), blk, 0, stream>>>(q_c, W_qdec, qb, Mz, Hz*Dz, QR, 0, 1, 64, DQK, 0);
    // k_rope raw -> kb[...,64:96]
    gemm_f32<<<dim3(Mz/64, (Hz*Rz)/64), blk, 0, stream>>>(x, W_krope, kb, Mz, Hz*Rz, Cz, 0, 1, 32, DQK, 64);
    // q_rope raw -> qb[...,64:96]
    gemm_f32<<<dim3(Mz/64, (Hz*Rz)/64), blk, 0, stream>>>(q_c, W_qrope, qb, Mz, Hz*Rz, QR, 0, 1, 32, DQK, 64);
    // RoPE in place on qb and kb rope slices
    rope_k<<<dim3((2 * BHT * 16) / 256), blk, 0, stream>>>(qb, kb);
    // attention
    attn_k<<<dim3(BHT), dim3(64), 0, stream>>>(qb, kb, vb, ob);
    // out = heads(ob) @ W_o
    gemm_f32<<<dim3(Mz/64, Cz/64), blk, 0, stream>>>(ob, W_o, out, Mz, Cz, Cz, 2, 0, 0, 0, 0);
}

// Round 2
// 912.906 us; speedup vs baseline: 4.9958x; 4.9958x over previous
//
#include <hip/hip_runtime.h>
#include <hip/hip_bf16.h>
#include <math.h>

// Problem constants
#define Bz 2
#define Tz 2048
#define Cz 1024
#define Hz 16
#define Dz 64      // HEAD_DIM
#define Rz 32      // ROPE_DIM
#define KVR 256
#define QR 512
#define DQK 96     // HEAD_DIM + ROPE_DIM
#define Mz (Bz*Tz)         // 4096 rows
#define BHT (Bz*Hz*Tz)     // 65536
#define QK_SCALE 0.10206207261596577f  // 1/sqrt(96)

typedef __attribute__((ext_vector_type(8))) short short8;
typedef __attribute__((ext_vector_type(4))) float f32x4;

__device__ __forceinline__ short f2bf(float f) {
    union { float f; unsigned u; } un; un.f = f;
    unsigned r = un.u + 0x7FFF + ((un.u >> 16) & 1);
    return (short)(r >> 16);
}
__device__ __forceinline__ float bf2f(unsigned short h) {
    union { unsigned u; float f; } un; un.u = ((unsigned)h) << 16; return un.f;
}

// ---------------------------------------------------------------------------
// Generic fp32 tiled GEMM:  C = A(MxK) @ W(KxN)
// amode 0: A row-major.  amode 2: A is heads buffer (B,H,T,64) read as (m,k)
// omode 0: C fp32 row-major
// omode 1: C bf16 scatter into (B,H,T,Dtot) at column offset `off`, *scale
// omode 3: C bf16 scatter into V^T layout (B,H,64,T), *scale
// ---------------------------------------------------------------------------
__device__ __forceinline__ float loadA(const float* __restrict__ A, int m, int kk,
                                       int K, int amode) {
    if (amode == 0) return A[(size_t)m * K + kk];
    int b = m >> 11, t = m & (Tz - 1);
    int h = kk >> 6, d = kk & 63;
    return A[(((size_t)b * Hz + h) * Tz + t) * 64 + d];
}

__global__ __launch_bounds__(256) void gemm_f32(
    const float* __restrict__ A, const float* __restrict__ W, void* __restrict__ Cp,
    int M, int N, int K, int amode, int omode, int headDim, int Dtot, int off,
    float scale)
{
    __shared__ float As[16][65];
    __shared__ float Bs[16][65];
    int tid = threadIdx.x;
    int tx = tid & 15, ty = tid >> 4;
    int bm = blockIdx.x * 64;
    int bn = blockIdx.y * 64;

    float acc[4][4] = {};

    for (int k0 = 0; k0 < K; k0 += 16) {
        #pragma unroll
        for (int l = 0; l < 4; l++) {
            int idx = tid + l * 256;
            int r = idx >> 4, c = idx & 15;
            As[c][r] = loadA(A, bm + r, k0 + c, K, amode);
        }
        #pragma unroll
        for (int l = 0; l < 4; l++) {
            int idx = tid + l * 256;
            int n = idx & 63, c = idx >> 6;
            Bs[c][n] = W[(size_t)(k0 + c) * N + bn + n];
        }
        __syncthreads();
        #pragma unroll
        for (int kk = 0; kk < 16; kk++) {
            float a[4], b[4];
            #pragma unroll
            for (int i = 0; i < 4; i++) a[i] = As[kk][ty * 4 + i];
            #pragma unroll
            for (int j = 0; j < 4; j++) b[j] = Bs[kk][tx * 4 + j];
            #pragma unroll
            for (int i = 0; i < 4; i++)
                #pragma unroll
                for (int j = 0; j < 4; j++)
                    acc[i][j] = fmaf(a[i], b[j], acc[i][j]);
        }
        __syncthreads();
    }

    #pragma unroll
    for (int i = 0; i < 4; i++) {
        int m = bm + ty * 4 + i;
        #pragma unroll
        for (int j = 0; j < 4; j++) {
            int n = bn + tx * 4 + j;
            float v = acc[i][j] * scale;
            if (omode == 0) {
                ((float*)Cp)[(size_t)m * N + n] = v;
            } else {
                int b = m >> 11, t = m & (Tz - 1);
                int h = n / headDim, dd = n % headDim;
                if (omode == 1)
                    ((unsigned short*)Cp)[((((size_t)b * Hz + h) * Tz + t) * Dtot) + off + dd] = (unsigned short)f2bf(v);
                else // omode 3: V^T (B,H,64,T)
                    ((unsigned short*)Cp)[((((size_t)b * Hz + h) * 64 + dd) * Tz) + t] = (unsigned short)f2bf(v);
            }
        }
    }
}

// ---------------------------------------------------------------------------
// RMSNorm over rows of 256, in place, with gain g. One wave per row.
// ---------------------------------------------------------------------------
__global__ __launch_bounds__(256) void rmsnorm_k(float* __restrict__ kv,
                                                 const float* __restrict__ g)
{
    int row = blockIdx.x * 4 + (threadIdx.x >> 6);
    int lane = threadIdx.x & 63;
    float* p = kv + (size_t)row * 256;
    float v[4];
    float ss = 0.f;
    #pragma unroll
    for (int i = 0; i < 4; i++) { v[i] = p[lane + i * 64]; ss += v[i] * v[i]; }
    #pragma unroll
    for (int o = 32; o > 0; o >>= 1) ss += __shfl_xor(ss, o);
    float r = rsqrtf(ss * (1.f / 256.f) + 1e-6f);
    #pragma unroll
    for (int i = 0; i < 4; i++) p[lane + i * 64] = v[i] * r * g[lane + i * 64];
}

// ---------------------------------------------------------------------------
// RoPE in place on the [64..96) slice of bf16 q and k (both (B,H,T,96)).
// ---------------------------------------------------------------------------
__global__ __launch_bounds__(256) void rope_bf16(unsigned short* __restrict__ qb,
                                                 unsigned short* __restrict__ kb)
{
    int idx = blockIdx.x * 256 + threadIdx.x;
    int j = idx & 15;
    int row = idx >> 4;          // 0 .. 2*BHT
    unsigned short* buf = (row >= BHT) ? kb : qb;
    if (row >= BHT) row -= BHT;
    int t = row & (Tz - 1);
    float inv = powf(10000.f, -(float)(2 * j) / 32.f);
    float ang = (float)t * inv;
    float cs = cosf(ang), sn = sinf(ang);
    unsigned short* pr = buf + (size_t)row * DQK + Dz;
    float x1 = bf2f(pr[j]), x2 = bf2f(pr[j + 16]);
    pr[j]      = (unsigned short)f2bf(x1 * cs - x2 * sn);
    pr[j + 16] = (unsigned short)f2bf(x2 * cs + x1 * sn);
}

// ---------------------------------------------------------------------------
// MFMA flash attention. 256 threads = 4 waves; block handles 64 q rows of one
// (b,h). q (B,H,T,96) bf16 pre-scaled; k (B,H,T,96) bf16; vt (B,H,64,T) bf16.
// o (B,H,T,64) fp32.
// ---------------------------------------------------------------------------
#define KS_STRIDE 104
#define VT_STRIDE 72
#define PS_STRIDE 72

__global__ __launch_bounds__(256) void attn_mfma(
    const unsigned short* __restrict__ q,
    const unsigned short* __restrict__ k,
    const unsigned short* __restrict__ vt,
    float* __restrict__ o)
{
    __shared__ __attribute__((aligned(16))) unsigned short Ks[64 * KS_STRIDE];
    __shared__ __attribute__((aligned(16))) unsigned short Vt_s[64 * VT_STRIDE];
    __shared__ __attribute__((aligned(16))) unsigned short Ps[64 * PS_STRIDE];

    int tid = threadIdx.x;
    int lane = tid & 63;
    int w = tid >> 6;                 // wave 0..3
    int c = lane & 15, g = lane >> 4; // fragment coords
    int bh = blockIdx.x >> 5;
    int qt = blockIdx.x & 31;
    int q0 = qt * 64;

    const unsigned short* qb = q + (size_t)bh * Tz * DQK;
    const unsigned short* kb = k + (size_t)bh * Tz * DQK;
    const unsigned short* vb = vt + (size_t)bh * 64 * Tz;

    // Q fragments in registers: wave strip rows q0+w*16 .. +15
    short8 qf[3];
    {
        const unsigned short* qrow = qb + (size_t)(q0 + w * 16 + c) * DQK;
        #pragma unroll
        for (int kc = 0; kc < 3; kc++)
            qf[kc] = *(const short8*)(qrow + kc * 32 + g * 8);
    }

    f32x4 oacc[4] = {};
    float mrun[4], lrun[4];
    #pragma unroll
    for (int r = 0; r < 4; r++) { mrun[r] = -1e30f; lrun[r] = 0.f; }

    for (int kt0 = 0; kt0 <= q0; kt0 += 64) {
        __syncthreads();   // protect LDS from previous iteration's readers

        // stage K tile: 64 rows x 96 bf16
        #pragma unroll
        for (int i = 0; i < 3; i++) {
            int idx = tid + i * 256;
            int row = idx / 12, c8 = idx % 12;
            *(short8*)&Ks[row * KS_STRIDE + c8 * 8] =
                *(const short8*)&kb[(size_t)(kt0 + row) * DQK + c8 * 8];
        }
        // stage V^T tile: 64 dims x 64 keys
        #pragma unroll
        for (int i = 0; i < 2; i++) {
            int idx = tid + i * 256;
            int d = idx >> 3, t8 = idx & 7;
            *(short8*)&Vt_s[d * VT_STRIDE + t8 * 8] =
                *(const short8*)&vb[(size_t)d * Tz + kt0 + t8 * 8];
        }
        __syncthreads();

        // S = Q @ K^T  (wave strip 16 x 64)
        f32x4 sacc[4] = {};
        #pragma unroll
        for (int kc = 0; kc < 3; kc++) {
            #pragma unroll
            for (int nt = 0; nt < 4; nt++) {
                short8 bfrag = *(const short8*)&Ks[(nt * 16 + c) * KS_STRIDE + kc * 32 + g * 8];
                sacc[nt] = __builtin_amdgcn_mfma_f32_16x16x32_bf16(qf[kc], bfrag, sacc[nt], 0, 0, 0);
            }
        }

        // causal mask (diagonal block only)
        if (kt0 == q0) {
            #pragma unroll
            for (int nt = 0; nt < 4; nt++)
                #pragma unroll
                for (int r = 0; r < 4; r++)
                    if (kt0 + nt * 16 + c > q0 + w * 16 + g * 4 + r)
                        sacc[nt][r] = -1e30f;
        }

        // online softmax (rows r of this lane's group)
        float pm[4], sc[4], rs[4], p[4][4];
        #pragma unroll
        for (int r = 0; r < 4; r++)
            pm[r] = fmaxf(fmaxf(sacc[0][r], sacc[1][r]), fmaxf(sacc[2][r], sacc[3][r]));
        #pragma unroll
        for (int r = 0; r < 4; r++) {
            #pragma unroll
            for (int off = 1; off < 16; off <<= 1)
                pm[r] = fmaxf(pm[r], __shfl_xor(pm[r], off));
        }
        #pragma unroll
        for (int r = 0; r < 4; r++) {
            float mn = fmaxf(mrun[r], pm[r]);
            sc[r] = __expf(mrun[r] - mn);
            mrun[r] = mn;
        }
        #pragma unroll
        for (int nt = 0; nt < 4; nt++)
            #pragma unroll
            for (int r = 0; r < 4; r++)
                p[nt][r] = __expf(sacc[nt][r] - mrun[r]);
        #pragma unroll
        for (int r = 0; r < 4; r++)
            rs[r] = p[0][r] + p[1][r] + p[2][r] + p[3][r];
        #pragma unroll
        for (int r = 0; r < 4; r++) {
            #pragma unroll
            for (int off = 1; off < 16; off <<= 1)
                rs[r] += __shfl_xor(rs[r], off);
            lrun[r] = lrun[r] * sc[r] + rs[r];
        }
        #pragma unroll
        for (int nt = 0; nt < 4; nt++)
            #pragma unroll
            for (int r = 0; r < 4; r++)
                oacc[nt][r] *= sc[r];

        // P -> LDS (bf16), per-wave strip
        #pragma unroll
        for (int nt = 0; nt < 4; nt++)
            #pragma unroll
            for (int r = 0; r < 4; r++)
                Ps[(w * 16 + g * 4 + r) * PS_STRIDE + nt * 16 + c] =
                    (unsigned short)f2bf(p[nt][r]);
        __syncthreads();

        // O += P @ V
        #pragma unroll
        for (int kc2 = 0; kc2 < 2; kc2++) {
            short8 pf = *(const short8*)&Ps[(w * 16 + c) * PS_STRIDE + kc2 * 32 + g * 8];
            #pragma unroll
            for (int nt = 0; nt < 4; nt++) {
                short8 vf = *(const short8*)&Vt_s[(nt * 16 + c) * VT_STRIDE + kc2 * 32 + g * 8];
                oacc[nt] = __builtin_amdgcn_mfma_f32_16x16x32_bf16(pf, vf, oacc[nt], 0, 0, 0);
            }
        }
    }

    // epilogue
    #pragma unroll
    for (int nt = 0; nt < 4; nt++)
        #pragma unroll
        for (int r = 0; r < 4; r++)
            o[((size_t)bh * Tz + q0 + w * 16 + g * 4 + r) * 64 + nt * 16 + c] =
                oacc[nt][r] / lrun[r];
}

// ---------------------------------------------------------------------------
extern "C" void kernel_launch(void* const* d_in, const int* in_sizes, int n_in,
                              void* d_out, int out_size, void* d_ws, size_t ws_size,
                              hipStream_t stream)
{
    const float* x       = (const float*)d_in[0];
    const float* W_kv    = (const float*)d_in[1];
    const float* g_kv    = (const float*)d_in[2];
    const float* W_kdec  = (const float*)d_in[3];
    const float* W_vdec  = (const float*)d_in[4];
    const float* W_q     = (const float*)d_in[5];
    const float* W_qdec  = (const float*)d_in[6];
    const float* W_krope = (const float*)d_in[7];
    const float* W_qrope = (const float*)d_in[8];
    const float* W_o     = (const float*)d_in[9];
    float* out = (float*)d_out;

    float* ws   = (float*)d_ws;
    float* kv_n = ws;                                 // 4096*256 f32
    float* q_c  = kv_n + (size_t)Mz * KVR;            // 4096*512 f32
    float* ob   = q_c  + (size_t)Mz * QR;             // BHT*64 f32
    unsigned short* qbb = (unsigned short*)(ob + (size_t)BHT * 64); // BHT*96 bf16
    unsigned short* kbb = qbb + (size_t)BHT * DQK;    // BHT*96 bf16
    unsigned short* vtb = kbb + (size_t)BHT * DQK;    // B*H*64*T bf16

    dim3 blk(256);

    // kv_c = x @ W_kv (fp32)
    gemm_f32<<<dim3(Mz/64, KVR/64), blk, 0, stream>>>(x, W_kv, kv_n, Mz, KVR, Cz, 0, 0, 0, 0, 0, 1.f);
    // RMSNorm in place
    rmsnorm_k<<<dim3(Mz/4), blk, 0, stream>>>(kv_n, g_kv);
    // q_c = x @ W_q (fp32)
    gemm_f32<<<dim3(Mz/64, QR/64), blk, 0, stream>>>(x, W_q, q_c, Mz, QR, Cz, 0, 0, 0, 0, 0, 1.f);
    // k_content -> kbb[...,0:64] bf16
    gemm_f32<<<dim3(Mz/64, (Hz*Dz)/64), blk, 0, stream>>>(kv_n, W_kdec, kbb, Mz, Hz*Dz, KVR, 0, 1, 64, DQK, 0, 1.f);
    // v -> vtb (B,H,64,T) bf16
    gemm_f32<<<dim3(Mz/64, (Hz*Dz)/64), blk, 0, stream>>>(kv_n, W_vdec, vtb, Mz, Hz*Dz, KVR, 0, 3, 64, 0, 0, 1.f);
    // q_content -> qbb[...,0:64] bf16, pre-scaled
    gemm_f32<<<dim3(Mz/64, (Hz*Dz)/64), blk, 0, stream>>>(q_c, W_qdec, qbb, Mz, Hz*Dz, QR, 0, 1, 64, DQK, 0, QK_SCALE);
    // k_rope -> kbb[...,64:96] bf16
    gemm_f32<<<dim3(Mz/64, (Hz*Rz)/64), blk, 0, stream>>>(x, W_krope, kbb, Mz, Hz*Rz, Cz, 0, 1, 32, DQK, 64, 1.f);
    // q_rope -> qbb[...,64:96] bf16, pre-scaled
    gemm_f32<<<dim3(Mz/64, (Hz*Rz)/64), blk, 0, stream>>>(q_c, W_qrope, qbb, Mz, Hz*Rz, QR, 0, 1, 32, DQK, 64, QK_SCALE);
    // RoPE in place on rope slices
    rope_bf16<<<dim3((2 * BHT * 16) / 256), blk, 0, stream>>>(qbb, kbb);
    // MFMA flash attention
    attn_mfma<<<dim3(Bz*Hz*(Tz/64)), blk, 0, stream>>>(qbb, kbb, vtb, ob);
    // out = heads(ob) @ W_o (fp32)
    gemm_f32<<<dim3(Mz/64, Cz/64), blk, 0, stream>>>(ob, W_o, out, Mz, Cz, Cz, 2, 0, 0, 0, 0, 1.f);
}

// Round 3
// 311.350 us; speedup vs baseline: 14.6482x; 2.9321x over previous
//
#include <hip/hip_runtime.h>
#include <hip/hip_bf16.h>
#include <math.h>

// Problem constants
#define Bz 2
#define Tz 2048
#define Cz 1024
#define Hz 16
#define Dz 64      // HEAD_DIM
#define Rz 32      // ROPE_DIM
#define KVR 256
#define QR 512
#define DQK 96     // HEAD_DIM + ROPE_DIM
#define Mz (Bz*Tz)         // 4096 rows
#define BHT (Bz*Hz*Tz)     // 65536
#define QK_SCALE 0.10206207261596577f  // 1/sqrt(96)

typedef __attribute__((ext_vector_type(8))) short short8;
typedef __attribute__((ext_vector_type(4))) float f32x4;
typedef __attribute__((ext_vector_type(4))) unsigned short ushort4v;

__device__ __forceinline__ unsigned short f2bf(float f) {
    union { float f; unsigned u; } un; un.f = f;
    unsigned r = un.u + 0x7FFF + ((un.u >> 16) & 1);
    return (unsigned short)(r >> 16);
}
__device__ __forceinline__ float bf2f(unsigned short h) {
    union { unsigned u; float f; } un; un.u = ((unsigned)h) << 16; return un.f;
}

// ---------------------------------------------------------------------------
// f32 -> bf16 straight convert (n multiple of 1024)
// ---------------------------------------------------------------------------
__global__ __launch_bounds__(256) void conv_f32_bf16(const float* __restrict__ in,
                                                     unsigned short* __restrict__ out,
                                                     int n)
{
    int i = (blockIdx.x * 256 + threadIdx.x) * 4;
    if (i >= n) return;
    float4 v = *(const float4*)&in[i];
    ushort4v o = { f2bf(v.x), f2bf(v.y), f2bf(v.z), f2bf(v.w) };
    *(ushort4v*)&out[i] = o;
}

// ---------------------------------------------------------------------------
// f32 (K x N) -> bf16 transposed (N x K). 32x32 LDS tiles, both sides coalesced.
// ---------------------------------------------------------------------------
__global__ __launch_bounds__(256) void transpose_conv(const float* __restrict__ in,
                                                      unsigned short* __restrict__ out,
                                                      int K, int N)
{
    __shared__ float ts[32][33];
    int k0 = blockIdx.x * 32, n0 = blockIdx.y * 32;
    int tid = threadIdx.x;
    int r = tid >> 5, cc = tid & 31;
    #pragma unroll
    for (int l = 0; l < 4; l++)
        ts[r + l * 8][cc] = in[(size_t)(k0 + r + l * 8) * N + n0 + cc];
    __syncthreads();
    #pragma unroll
    for (int l = 0; l < 4; l++)
        out[(size_t)(n0 + r + l * 8) * K + k0 + cc] = f2bf(ts[cc][r + l * 8]);
}

// ---------------------------------------------------------------------------
// bf16 MFMA GEMM: C = A(MxK) @ W(KxN), W given TRANSPOSED (Wt is N x K).
// 64x64 tile, BK=64, 4 waves (wave w: rows w*16..+15, all 64 cols).
// amode 0: A bf16 row-major. amode 2: A bf16 heads buffer (B,H,T,64).
// omode 0: C fp32 row-major
// omode 1: C bf16 scatter (B,H,T,Dtot)+off
// omode 3: C bf16 scatter V^T (B,H,64,T)
// omode 5: C bf16 row-major
// ---------------------------------------------------------------------------
__global__ __launch_bounds__(256) void gemm_mfma(
    const unsigned short* __restrict__ A, const unsigned short* __restrict__ Wt,
    void* __restrict__ Cp, int M, int N, int K,
    int amode, int omode, int headDim, int Dtot, int off, float scale)
{
    __shared__ __attribute__((aligned(16))) unsigned short As[64 * 72];
    __shared__ __attribute__((aligned(16))) unsigned short Bs[64 * 72];

    int tid = threadIdx.x, lane = tid & 63, w = tid >> 6;
    int c = lane & 15, g = lane >> 4;
    int m0 = blockIdx.x * 64, n0 = blockIdx.y * 64;

    f32x4 acc[4] = {};

    for (int k0 = 0; k0 < K; k0 += 64) {
        #pragma unroll
        for (int l = 0; l < 2; l++) {
            int idx = tid + l * 256;
            int row = idx >> 3, c8 = idx & 7;
            // A tile row-major (rows = M, cols = K chunk)
            const unsigned short* srcA;
            if (amode == 0) {
                srcA = &A[(size_t)(m0 + row) * K + k0 + c8 * 8];
            } else {
                int m = m0 + row;
                int b = m >> 11, t = m & (Tz - 1);
                int kk = k0 + c8 * 8;
                int h = kk >> 6, d = kk & 63;
                srcA = &A[(((size_t)b * Hz + h) * Tz + t) * 64 + d];
            }
            *(short8*)&As[row * 72 + c8 * 8] = *(const short8*)srcA;
            // B tile: Bs[n][k], Wt row-major N x K
            *(short8*)&Bs[row * 72 + c8 * 8] =
                *(const short8*)&Wt[(size_t)(n0 + row) * K + k0 + c8 * 8];
        }
        __syncthreads();

        #pragma unroll
        for (int ks = 0; ks < 64; ks += 32) {
            short8 af = *(const short8*)&As[(w * 16 + c) * 72 + ks + g * 8];
            #pragma unroll
            for (int nt = 0; nt < 4; nt++) {
                short8 bf = *(const short8*)&Bs[(nt * 16 + c) * 72 + ks + g * 8];
                acc[nt] = __builtin_amdgcn_mfma_f32_16x16x32_bf16(af, bf, acc[nt], 0, 0, 0);
            }
        }
        __syncthreads();
    }

    #pragma unroll
    for (int nt = 0; nt < 4; nt++) {
        #pragma unroll
        for (int r = 0; r < 4; r++) {
            int m = m0 + w * 16 + g * 4 + r;
            int n = n0 + nt * 16 + c;
            float v = acc[nt][r] * scale;
            if (omode == 0) {
                ((float*)Cp)[(size_t)m * N + n] = v;
            } else if (omode == 5) {
                ((unsigned short*)Cp)[(size_t)m * N + n] = f2bf(v);
            } else {
                int b = m >> 11, t = m & (Tz - 1);
                int h = n / headDim, dd = n % headDim;
                if (omode == 1)
                    ((unsigned short*)Cp)[((((size_t)b * Hz + h) * Tz + t) * Dtot) + off + dd] = f2bf(v);
                else // omode 3: V^T (B,H,64,T)
                    ((unsigned short*)Cp)[((((size_t)b * Hz + h) * 64 + dd) * Tz) + t] = f2bf(v);
            }
        }
    }
}

// ---------------------------------------------------------------------------
// RMSNorm over rows of 256: fp32 in, bf16 out, gain g. One wave per row.
// ---------------------------------------------------------------------------
__global__ __launch_bounds__(256) void rmsnorm_k(const float* __restrict__ kv,
                                                 const float* __restrict__ g,
                                                 unsigned short* __restrict__ outb)
{
    int row = blockIdx.x * 4 + (threadIdx.x >> 6);
    int lane = threadIdx.x & 63;
    const float* p = kv + (size_t)row * 256;
    float v[4];
    float ss = 0.f;
    #pragma unroll
    for (int i = 0; i < 4; i++) { v[i] = p[lane + i * 64]; ss += v[i] * v[i]; }
    #pragma unroll
    for (int o = 32; o > 0; o >>= 1) ss += __shfl_xor(ss, o);
    float r = rsqrtf(ss * (1.f / 256.f) + 1e-6f);
    #pragma unroll
    for (int i = 0; i < 4; i++)
        outb[(size_t)row * 256 + lane + i * 64] = f2bf(v[i] * r * g[lane + i * 64]);
}

// ---------------------------------------------------------------------------
// RoPE in place on the [64..96) slice of bf16 q and k (both (B,H,T,96)).
// ---------------------------------------------------------------------------
__global__ __launch_bounds__(256) void rope_bf16(unsigned short* __restrict__ qb,
                                                 unsigned short* __restrict__ kb)
{
    int idx = blockIdx.x * 256 + threadIdx.x;
    int j = idx & 15;
    int row = idx >> 4;          // 0 .. 2*BHT
    unsigned short* buf = (row >= BHT) ? kb : qb;
    if (row >= BHT) row -= BHT;
    int t = row & (Tz - 1);
    float inv = powf(10000.f, -(float)(2 * j) / 32.f);
    float ang = (float)t * inv;
    float cs = cosf(ang), sn = sinf(ang);
    unsigned short* pr = buf + (size_t)row * DQK + Dz;
    float x1 = bf2f(pr[j]), x2 = bf2f(pr[j + 16]);
    pr[j]      = f2bf(x1 * cs - x2 * sn);
    pr[j + 16] = f2bf(x2 * cs + x1 * sn);
}

// ---------------------------------------------------------------------------
// MFMA flash attention. 256 threads = 4 waves; block handles 64 q rows of one
// (b,h). q (B,H,T,96) bf16 pre-scaled; k (B,H,T,96) bf16; vt (B,H,64,T) bf16.
// o (B,H,T,64) bf16.
// ---------------------------------------------------------------------------
#define KS_STRIDE 104
#define VT_STRIDE 72
#define PS_STRIDE 72

__global__ __launch_bounds__(256) void attn_mfma(
    const unsigned short* __restrict__ q,
    const unsigned short* __restrict__ k,
    const unsigned short* __restrict__ vt,
    unsigned short* __restrict__ o)
{
    __shared__ __attribute__((aligned(16))) unsigned short Ks[64 * KS_STRIDE];
    __shared__ __attribute__((aligned(16))) unsigned short Vt_s[64 * VT_STRIDE];
    __shared__ __attribute__((aligned(16))) unsigned short Ps[64 * PS_STRIDE];

    int tid = threadIdx.x;
    int lane = tid & 63;
    int w = tid >> 6;                 // wave 0..3
    int c = lane & 15, g = lane >> 4; // fragment coords
    int bh = blockIdx.x >> 5;
    int qt = blockIdx.x & 31;
    int q0 = qt * 64;

    const unsigned short* qb = q + (size_t)bh * Tz * DQK;
    const unsigned short* kb = k + (size_t)bh * Tz * DQK;
    const unsigned short* vb = vt + (size_t)bh * 64 * Tz;

    short8 qf[3];
    {
        const unsigned short* qrow = qb + (size_t)(q0 + w * 16 + c) * DQK;
        #pragma unroll
        for (int kc = 0; kc < 3; kc++)
            qf[kc] = *(const short8*)(qrow + kc * 32 + g * 8);
    }

    f32x4 oacc[4] = {};
    float mrun[4], lrun[4];
    #pragma unroll
    for (int r = 0; r < 4; r++) { mrun[r] = -1e30f; lrun[r] = 0.f; }

    for (int kt0 = 0; kt0 <= q0; kt0 += 64) {
        __syncthreads();

        #pragma unroll
        for (int i = 0; i < 3; i++) {
            int idx = tid + i * 256;
            int row = idx / 12, c8 = idx % 12;
            *(short8*)&Ks[row * KS_STRIDE + c8 * 8] =
                *(const short8*)&kb[(size_t)(kt0 + row) * DQK + c8 * 8];
        }
        #pragma unroll
        for (int i = 0; i < 2; i++) {
            int idx = tid + i * 256;
            int d = idx >> 3, t8 = idx & 7;
            *(short8*)&Vt_s[d * VT_STRIDE + t8 * 8] =
                *(const short8*)&vb[(size_t)d * Tz + kt0 + t8 * 8];
        }
        __syncthreads();

        f32x4 sacc[4] = {};
        #pragma unroll
        for (int kc = 0; kc < 3; kc++) {
            #pragma unroll
            for (int nt = 0; nt < 4; nt++) {
                short8 bfrag = *(const short8*)&Ks[(nt * 16 + c) * KS_STRIDE + kc * 32 + g * 8];
                sacc[nt] = __builtin_amdgcn_mfma_f32_16x16x32_bf16(qf[kc], bfrag, sacc[nt], 0, 0, 0);
            }
        }

        if (kt0 == q0) {
            #pragma unroll
            for (int nt = 0; nt < 4; nt++)
                #pragma unroll
                for (int r = 0; r < 4; r++)
                    if (kt0 + nt * 16 + c > q0 + w * 16 + g * 4 + r)
                        sacc[nt][r] = -1e30f;
        }

        float pm[4], sc[4], rs[4], p[4][4];
        #pragma unroll
        for (int r = 0; r < 4; r++)
            pm[r] = fmaxf(fmaxf(sacc[0][r], sacc[1][r]), fmaxf(sacc[2][r], sacc[3][r]));
        #pragma unroll
        for (int r = 0; r < 4; r++) {
            #pragma unroll
            for (int off = 1; off < 16; off <<= 1)
                pm[r] = fmaxf(pm[r], __shfl_xor(pm[r], off));
        }
        #pragma unroll
        for (int r = 0; r < 4; r++) {
            float mn = fmaxf(mrun[r], pm[r]);
            sc[r] = __expf(mrun[r] - mn);
            mrun[r] = mn;
        }
        #pragma unroll
        for (int nt = 0; nt < 4; nt++)
            #pragma unroll
            for (int r = 0; r < 4; r++)
                p[nt][r] = __expf(sacc[nt][r] - mrun[r]);
        #pragma unroll
        for (int r = 0; r < 4; r++)
            rs[r] = p[0][r] + p[1][r] + p[2][r] + p[3][r];
        #pragma unroll
        for (int r = 0; r < 4; r++) {
            #pragma unroll
            for (int off = 1; off < 16; off <<= 1)
                rs[r] += __shfl_xor(rs[r], off);
            lrun[r] = lrun[r] * sc[r] + rs[r];
        }
        #pragma unroll
        for (int nt = 0; nt < 4; nt++)
            #pragma unroll
            for (int r = 0; r < 4; r++)
                oacc[nt][r] *= sc[r];

        #pragma unroll
        for (int nt = 0; nt < 4; nt++)
            #pragma unroll
            for (int r = 0; r < 4; r++)
                Ps[(w * 16 + g * 4 + r) * PS_STRIDE + nt * 16 + c] = f2bf(p[nt][r]);
        __syncthreads();

        #pragma unroll
        for (int kc2 = 0; kc2 < 2; kc2++) {
            short8 pf = *(const short8*)&Ps[(w * 16 + c) * PS_STRIDE + kc2 * 32 + g * 8];
            #pragma unroll
            for (int nt = 0; nt < 4; nt++) {
                short8 vf = *(const short8*)&Vt_s[(nt * 16 + c) * VT_STRIDE + kc2 * 32 + g * 8];
                oacc[nt] = __builtin_amdgcn_mfma_f32_16x16x32_bf16(pf, vf, oacc[nt], 0, 0, 0);
            }
        }
    }

    #pragma unroll
    for (int nt = 0; nt < 4; nt++)
        #pragma unroll
        for (int r = 0; r < 4; r++)
            o[((size_t)bh * Tz + q0 + w * 16 + g * 4 + r) * 64 + nt * 16 + c] =
                f2bf(oacc[nt][r] / lrun[r]);
}

// ---------------------------------------------------------------------------
extern "C" void kernel_launch(void* const* d_in, const int* in_sizes, int n_in,
                              void* d_out, int out_size, void* d_ws, size_t ws_size,
                              hipStream_t stream)
{
    const float* x       = (const float*)d_in[0];
    const float* W_kv    = (const float*)d_in[1];
    const float* g_kv    = (const float*)d_in[2];
    const float* W_kdec  = (const float*)d_in[3];
    const float* W_vdec  = (const float*)d_in[4];
    const float* W_q     = (const float*)d_in[5];
    const float* W_qdec  = (const float*)d_in[6];
    const float* W_krope = (const float*)d_in[7];
    const float* W_qrope = (const float*)d_in[8];
    const float* W_o     = (const float*)d_in[9];
    float* out = (float*)d_out;

    float* kv_f32 = (float*)d_ws;                           // 4096*256 f32
    unsigned short* us = (unsigned short*)(kv_f32 + (size_t)Mz * KVR);
    unsigned short* x_bf  = us;               us += (size_t)Mz * Cz;
    unsigned short* kv_bf = us;               us += (size_t)Mz * KVR;
    unsigned short* qc_bf = us;               us += (size_t)Mz * QR;
    unsigned short* qbb   = us;               us += (size_t)BHT * DQK;
    unsigned short* kbb   = us;               us += (size_t)BHT * DQK;
    unsigned short* vtb   = us;               us += (size_t)BHT * 64;
    unsigned short* ob    = us;               us += (size_t)BHT * 64;
    unsigned short* wkvT  = us;               us += (size_t)KVR * Cz;
    unsigned short* wqT   = us;               us += (size_t)QR * Cz;
    unsigned short* wkdT  = us;               us += (size_t)(Hz*Dz) * KVR;
    unsigned short* wvdT  = us;               us += (size_t)(Hz*Dz) * KVR;
    unsigned short* wqdT  = us;               us += (size_t)(Hz*Dz) * QR;
    unsigned short* wkrT  = us;               us += (size_t)(Hz*Rz) * Cz;
    unsigned short* wqrT  = us;               us += (size_t)(Hz*Rz) * QR;
    unsigned short* woT   = us;               us += (size_t)Cz * Cz;

    dim3 blk(256);

    // Converts
    conv_f32_bf16<<<dim3((Mz*Cz)/1024), blk, 0, stream>>>(x, x_bf, Mz*Cz);
    transpose_conv<<<dim3(Cz/32, KVR/32), blk, 0, stream>>>(W_kv,    wkvT, Cz,  KVR);
    transpose_conv<<<dim3(Cz/32, QR/32),  blk, 0, stream>>>(W_q,     wqT,  Cz,  QR);
    transpose_conv<<<dim3(KVR/32, (Hz*Dz)/32), blk, 0, stream>>>(W_kdec, wkdT, KVR, Hz*Dz);
    transpose_conv<<<dim3(KVR/32, (Hz*Dz)/32), blk, 0, stream>>>(W_vdec, wvdT, KVR, Hz*Dz);
    transpose_conv<<<dim3(QR/32, (Hz*Dz)/32),  blk, 0, stream>>>(W_qdec, wqdT, QR,  Hz*Dz);
    transpose_conv<<<dim3(Cz/32, (Hz*Rz)/32),  blk, 0, stream>>>(W_krope, wkrT, Cz, Hz*Rz);
    transpose_conv<<<dim3(QR/32, (Hz*Rz)/32),  blk, 0, stream>>>(W_qrope, wqrT, QR, Hz*Rz);
    transpose_conv<<<dim3(Cz/32, Cz/32),       blk, 0, stream>>>(W_o,    woT,  Cz,  Cz);

    // kv_c = x @ W_kv (fp32 out for RMSNorm)
    gemm_mfma<<<dim3(Mz/64, KVR/64), blk, 0, stream>>>(x_bf, wkvT, kv_f32, Mz, KVR, Cz, 0, 0, 0, 0, 0, 1.f);
    // RMSNorm -> bf16
    rmsnorm_k<<<dim3(Mz/4), blk, 0, stream>>>(kv_f32, g_kv, kv_bf);
    // q_c = x @ W_q (bf16 row-major)
    gemm_mfma<<<dim3(Mz/64, QR/64), blk, 0, stream>>>(x_bf, wqT, qc_bf, Mz, QR, Cz, 0, 5, 0, 0, 0, 1.f);
    // k_content -> kbb[...,0:64]
    gemm_mfma<<<dim3(Mz/64, (Hz*Dz)/64), blk, 0, stream>>>(kv_bf, wkdT, kbb, Mz, Hz*Dz, KVR, 0, 1, 64, DQK, 0, 1.f);
    // v -> vtb (B,H,64,T)
    gemm_mfma<<<dim3(Mz/64, (Hz*Dz)/64), blk, 0, stream>>>(kv_bf, wvdT, vtb, Mz, Hz*Dz, KVR, 0, 3, 64, 0, 0, 1.f);
    // q_content -> qbb[...,0:64], pre-scaled
    gemm_mfma<<<dim3(Mz/64, (Hz*Dz)/64), blk, 0, stream>>>(qc_bf, wqdT, qbb, Mz, Hz*Dz, QR, 0, 1, 64, DQK, 0, QK_SCALE);
    // k_rope -> kbb[...,64:96]
    gemm_mfma<<<dim3(Mz/64, (Hz*Rz)/64), blk, 0, stream>>>(x_bf, wkrT, kbb, Mz, Hz*Rz, Cz, 0, 1, 32, DQK, 64, 1.f);
    // q_rope -> qbb[...,64:96], pre-scaled
    gemm_mfma<<<dim3(Mz/64, (Hz*Rz)/64), blk, 0, stream>>>(qc_bf, wqrT, qbb, Mz, Hz*Rz, QR, 0, 1, 32, DQK, 64, QK_SCALE);
    // RoPE in place
    rope_bf16<<<dim3((2 * BHT * 16) / 256), blk, 0, stream>>>(qbb, kbb);
    // MFMA flash attention -> bf16 heads buffer
    attn_mfma<<<dim3(Bz*Hz*(Tz/64)), blk, 0, stream>>>(qbb, kbb, vtb, ob);
    // out = heads(ob) @ W_o (fp32 out)
    gemm_mfma<<<dim3(Mz/64, Cz/64), blk, 0, stream>>>(ob, woT, out, Mz, Cz, Cz, 2, 0, 0, 0, 0, 1.f);
}